// Round 2
// baseline (327.220 us; speedup 1.0000x reference)
//
#include <hip/hip_runtime.h>

#define NHW 9216   // 96*96
#define NB 2

typedef short s8v __attribute__((ext_vector_type(8)));     // 8 bf16 in 4 VGPRs
typedef float f4v __attribute__((ext_vector_type(4)));

__device__ inline unsigned short f2bf(float x) {
    unsigned int u = __float_as_uint(x);
    u += 0x7fffu + ((u >> 16) & 1u);          // round-to-nearest-even
    return (unsigned short)(u >> 16);
}
__device__ inline float bf2f(unsigned short h) {
    return __uint_as_float(((unsigned int)h) << 16);
}

// ---------------------------------------------------------------------------
// K1/K2: fp32 SGEMM  C[b][m][n] = sum_k A[m][k] * B[b][k][n] + bias[m] (opt relu)
// tile 64(M) x 128(N), BK=16, block 256, micro 4x(4+4)
// ---------------------------------------------------------------------------
__global__ __launch_bounds__(256) void k_sgemm(const float* __restrict__ A,
                                               const float* __restrict__ Bm,
                                               const float* __restrict__ bias,
                                               float* __restrict__ C,
                                               int M, int K, int relu)
{
    __shared__ float As[16][68];    // As[k][m], padded
    __shared__ float Bs[16][132];   // Bs[k][n], padded
    const int tid = threadIdx.x;
    const int tm = tid >> 4, tn = tid & 15;
    const int b  = blockIdx.z;
    const int m0 = blockIdx.y * 64, n0 = blockIdx.x * 128;
    const float* Bb = Bm + (size_t)b * K * NHW;
    float*       Cb = C  + (size_t)b * M * NHW;

    float acc[4][8];
#pragma unroll
    for (int i = 0; i < 4; ++i)
#pragma unroll
        for (int j = 0; j < 8; ++j) acc[i][j] = 0.f;

    for (int kt = 0; kt < K; kt += 16) {
        __syncthreads();
#pragma unroll
        for (int r = 0; r < 4; ++r) {           // A tile 64x16 -> As[k][m]
            int e = r * 256 + tid;
            int m = e >> 4, kk = e & 15;
            As[kk][m] = A[(size_t)(m0 + m) * K + kt + kk];
        }
#pragma unroll
        for (int r = 0; r < 2; ++r) {           // B tile 16x128
            int e = r * 256 + tid;
            int kk = e >> 5, n4 = e & 31;
            *(f4v*)&Bs[kk][n4 * 4] = *(const f4v*)&Bb[(size_t)(kt + kk) * NHW + n0 + n4 * 4];
        }
        __syncthreads();
#pragma unroll
        for (int kk = 0; kk < 16; ++kk) {
            f4v a  = *(const f4v*)&As[kk][tm * 4];
            f4v b1 = *(const f4v*)&Bs[kk][tn * 4];
            f4v b2 = *(const f4v*)&Bs[kk][tn * 4 + 64];
#pragma unroll
            for (int i = 0; i < 4; ++i)
#pragma unroll
                for (int j = 0; j < 4; ++j) {
                    acc[i][j]     += a[i] * b1[j];
                    acc[i][j + 4] += a[i] * b2[j];
                }
        }
    }
#pragma unroll
    for (int i = 0; i < 4; ++i) {
        int m = m0 + tm * 4 + i;
        float bs = bias[m];
        f4v o1, o2;
#pragma unroll
        for (int j = 0; j < 4; ++j) {
            float v1 = acc[i][j] + bs, v2 = acc[i][j + 4] + bs;
            if (relu) { v1 = fmaxf(v1, 0.f); v2 = fmaxf(v2, 0.f); }
            o1[j] = v1; o2[j] = v2;
        }
        *(f4v*)&Cb[(size_t)m * NHW + n0 + tn * 4]      = o1;
        *(f4v*)&Cb[(size_t)m * NHW + n0 + tn * 4 + 64] = o2;
    }
}

// ---------------------------------------------------------------------------
// K2b: per-pixel L2 normalize + transpose (c-major -> pixel-major) + bf16 hi/lo split
// block 256 = 64 pixels x 4 channel-groups of 32
// ---------------------------------------------------------------------------
__global__ __launch_bounds__(256) void k_norm(const float* __restrict__ feat,
                                              float* __restrict__ rf,
                                              unsigned short* __restrict__ hi,
                                              unsigned short* __restrict__ lo)
{
    __shared__ float fs[128][66];
    const int tid = threadIdx.x;
    const int b = blockIdx.y;
    const int p0 = blockIdx.x * 64;
    const size_t fb = (size_t)b * 128 * NHW;
#pragma unroll
    for (int r = 0; r < 32; ++r) {
        int e = r * 256 + tid;
        int c = e >> 6, p = e & 63;
        fs[c][p] = feat[fb + (size_t)c * NHW + p0 + p];
    }
    __syncthreads();
    const int pix = tid >> 2, cg = tid & 3;
    const int c0 = cg * 32;
    float ss = 0.f;
#pragma unroll
    for (int i = 0; i < 32; ++i) { float v = fs[c0 + i][pix]; ss += v * v; }
    ss += __shfl_xor(ss, 1, 64);
    ss += __shfl_xor(ss, 2, 64);
    const float mx = fmaxf(sqrtf(ss), 1e-12f);
    const size_t ro = ((size_t)b * NHW + p0 + pix) * 128 + c0;
#pragma unroll
    for (int i = 0; i < 32; ++i) {
        float v = fs[c0 + i][pix] / mx;
        rf[ro + i] = v;
        unsigned short h = f2bf(v);
        hi[ro + i] = h;
        lo[ro + i] = f2bf(v - bf2f(h));
    }
}

// ---------------------------------------------------------------------------
// K3: sim = rf . rf^T via 3-term bf16-split MFMA, running off-diag argmax/row.
// block 256 (4 waves), 128 rows/block (32/wave), col chunk = 1152 (18 tiles of 64)
// ---------------------------------------------------------------------------
__global__ __launch_bounds__(256) void k_simtop(const unsigned short* __restrict__ hi,
                                                const unsigned short* __restrict__ lo,
                                                float* __restrict__ cval,
                                                int* __restrict__ cidx)
{
    // frag-contiguous B staging: chunk id = split*16 + kf*4 + cs ; each chunk 64 lanes x 16B
    __shared__ unsigned short Bs[32][512];
    const int tid  = threadIdx.x;
    const int wave = tid >> 6, l = tid & 63, l15 = l & 15, q = l >> 4;
    const int b     = blockIdx.z;
    const int rbase = blockIdx.x * 128;
    const int chunk = blockIdx.y;
    const int cbase = chunk * 1152;
    const size_t base = (size_t)b * NHW;
    const int wr0 = rbase + wave * 32;

    // A fragments in registers: 2 row-subtiles x 4 k-frags, hi+lo
    s8v ah[2][4], al[2][4];
#pragma unroll
    for (int s = 0; s < 2; ++s) {
        int row = wr0 + s * 16 + l15;
#pragma unroll
        for (int kf = 0; kf < 4; ++kf) {
            int k = kf * 32 + q * 8;
            ah[s][kf] = *(const s8v*)&hi[(base + row) * 128 + k];
            al[s][kf] = *(const s8v*)&lo[(base + row) * 128 + k];
        }
    }

    float bv[2][4]; int bi[2][4];
#pragma unroll
    for (int s = 0; s < 2; ++s)
#pragma unroll
        for (int r = 0; r < 4; ++r) { bv[s][r] = -2.0f; bi[s][r] = 0; }

    for (int ct = 0; ct < 18; ++ct) {
        const int colt = cbase + ct * 64;
        __syncthreads();
#pragma unroll
        for (int r = 0; r < 8; ++r) {           // stage 32 KB, 8 chunks per wave
            int cid = r * 4 + wave;
            int split = cid >> 4, kf = (cid >> 2) & 3, cs = cid & 3;
            int col = colt + cs * 16 + l15;
            int k = kf * 32 + q * 8;
            const unsigned short* src = (split ? lo : hi) + (base + col) * 128 + k;
            *(s8v*)&Bs[cid][l * 8] = *(const s8v*)src;
        }
        __syncthreads();

        f4v acc[2][4];
#pragma unroll
        for (int s = 0; s < 2; ++s)
#pragma unroll
            for (int c = 0; c < 4; ++c) acc[s][c] = (f4v){0.f, 0.f, 0.f, 0.f};

#pragma unroll
        for (int kf = 0; kf < 4; ++kf) {
            s8v bh[4], bl[4];
#pragma unroll
            for (int cs = 0; cs < 4; ++cs) {
                bh[cs] = *(const s8v*)&Bs[kf * 4 + cs][l * 8];
                bl[cs] = *(const s8v*)&Bs[16 + kf * 4 + cs][l * 8];
            }
#pragma unroll
            for (int cs = 0; cs < 4; ++cs)
#pragma unroll
                for (int s = 0; s < 2; ++s)
                    acc[s][cs] = __builtin_amdgcn_mfma_f32_16x16x32_bf16(ah[s][kf], bh[cs], acc[s][cs], 0, 0, 0);
#pragma unroll
            for (int cs = 0; cs < 4; ++cs)
#pragma unroll
                for (int s = 0; s < 2; ++s)
                    acc[s][cs] = __builtin_amdgcn_mfma_f32_16x16x32_bf16(ah[s][kf], bl[cs], acc[s][cs], 0, 0, 0);
#pragma unroll
            for (int cs = 0; cs < 4; ++cs)
#pragma unroll
                for (int s = 0; s < 2; ++s)
                    acc[s][cs] = __builtin_amdgcn_mfma_f32_16x16x32_bf16(al[s][kf], bh[cs], acc[s][cs], 0, 0, 0);
        }

        // running off-diagonal argmax (C layout: col = lane&15, row = q*4 + reg)
        const bool hasdiag = (colt < wr0 + 32) && (wr0 < colt + 64);
        if (hasdiag) {
#pragma unroll
            for (int s = 0; s < 2; ++s)
#pragma unroll
                for (int cs = 0; cs < 4; ++cs) {
                    int c = colt + cs * 16 + l15;
#pragma unroll
                    for (int r = 0; r < 4; ++r) {
                        float v = acc[s][cs][r];
                        int rr = wr0 + s * 16 + q * 4 + r;
                        bool p = (v > bv[s][r]) && (c != rr);
                        bv[s][r] = p ? v : bv[s][r];
                        bi[s][r] = p ? c : bi[s][r];
                    }
                }
        } else {
#pragma unroll
            for (int s = 0; s < 2; ++s)
#pragma unroll
                for (int cs = 0; cs < 4; ++cs) {
                    int c = colt + cs * 16 + l15;
#pragma unroll
                    for (int r = 0; r < 4; ++r) {
                        float v = acc[s][cs][r];
                        bool p = v > bv[s][r];
                        bv[s][r] = p ? v : bv[s][r];
                        bi[s][r] = p ? c : bi[s][r];
                    }
                }
        }
    }

    // merge across the 16 lanes sharing each row (tie: lower index)
#pragma unroll
    for (int d = 1; d < 16; d <<= 1) {
#pragma unroll
        for (int s = 0; s < 2; ++s)
#pragma unroll
            for (int r = 0; r < 4; ++r) {
                float ov = __shfl_xor(bv[s][r], d, 64);
                int   oi = __shfl_xor(bi[s][r], d, 64);
                bool p = (ov > bv[s][r]) || (ov == bv[s][r] && oi < bi[s][r]);
                bv[s][r] = p ? ov : bv[s][r];
                bi[s][r] = p ? oi : bi[s][r];
            }
    }
    if (l15 == 0) {
#pragma unroll
        for (int s = 0; s < 2; ++s)
#pragma unroll
            for (int r = 0; r < 4; ++r) {
                int row = wr0 + s * 16 + q * 4 + r;
                cval[(base + row) * 8 + chunk] = bv[s][r];
                cidx[(base + row) * 8 + chunk] = bi[s][r];
            }
    }
}

// ---------------------------------------------------------------------------
// K4: merge 8 chunk candidates per row, gather neighbor, exact fp32 distance + mask
// block 256 = 16 rows x 16 lanes
// ---------------------------------------------------------------------------
__global__ __launch_bounds__(256) void k_finish(const float* __restrict__ rf,
                                                const float* __restrict__ cval,
                                                const int* __restrict__ cidx,
                                                float* __restrict__ out)
{
    const int tid = threadIdx.x;
    const int g = blockIdx.x * 16 + (tid >> 4);   // global row in [0, 18432)
    const int l15 = tid & 15;
    const int b = g / NHW, r = g - b * NHW;

    float bvv = -2.f; int bii = 0;
#pragma unroll
    for (int ch = 0; ch < 8; ++ch) {
        float v = cval[(size_t)g * 8 + ch];
        int   i = cidx[(size_t)g * 8 + ch];
        bool p = (v > bvv) || (v == bvv && i < bii);
        bvv = p ? v : bvv;
        bii = p ? i : bii;
    }
    const float* x = rf + ((size_t)b * NHW + r)   * 128;
    const float* y = rf + ((size_t)b * NHW + bii) * 128;
    float ss = 0.f;
#pragma unroll
    for (int j = 0; j < 2; ++j) {
        f4v a = *(const f4v*)&x[l15 * 8 + j * 4];
        f4v c = *(const f4v*)&y[l15 * 8 + j * 4];
        float d0 = a[0] - c[0], d1 = a[1] - c[1], d2 = a[2] - c[2], d3 = a[3] - c[3];
        ss += d0 * d0 + d1 * d1 + d2 * d2 + d3 * d3;
    }
#pragma unroll
    for (int d = 1; d < 16; d <<= 1) ss += __shfl_xor(ss, d, 64);
    if (l15 == 0) {
        float dist = sqrtf(ss);
        out[NB * NHW + g] = dist;                 // distance (B, 9216)
        out[g] = dist > 0.2f ? 1.0f : 0.0f;       // mask (B,1,96,96)
    }
}

// ---------------------------------------------------------------------------
extern "C" void kernel_launch(void* const* d_in, const int* in_sizes, int n_in,
                              void* d_out, int out_size, void* d_ws, size_t ws_size,
                              hipStream_t stream) {
    const float* features = (const float*)d_in[0];
    const float* W1 = (const float*)d_in[1];
    const float* b1 = (const float*)d_in[2];
    const float* W2 = (const float*)d_in[3];
    const float* b2 = (const float*)d_in[4];
    float* out = (float*)d_out;
    float* ws  = (float*)d_ws;

    // ws layout (floats), peak usage 7,077,888 floats = 28.3 MB:
    //   [0,        2359296)  feat   (dead after k_norm -> reused by cval/cidx)
    //   [2359296,  7077888)  h      (dead after k_sgemm#2)
    //   [2359296,  4718592)  rf     (aliases h lower half)
    //   [4718592,  5898240)  hi     (2359296 shorts, aliases h upper half)
    //   [5898240,  7077888)  lo     (2359296 shorts)
    //   [0,        147456)   cval   (aliases feat — k_norm done before k_simtop)
    //   [147456,   294912)   cidx
    float*          feat = ws;
    float*          h    = ws + 2359296;
    float*          rf   = ws + 2359296;
    unsigned short* hi   = (unsigned short*)(ws + 4718592);
    unsigned short* lo   = hi + 2359296;
    float*          cval = ws;
    int*            cidx = (int*)(ws + 147456);

    // conv1: h = relu(W1 @ X + b1)    (M=256, K=384)
    k_sgemm<<<dim3(72, 4, NB), 256, 0, stream>>>(W1, features, b1, h, 256, 384, 1);
    // conv2: feat = W2 @ h + b2       (M=128, K=256)
    k_sgemm<<<dim3(72, 2, NB), 256, 0, stream>>>(W2, h, b2, feat, 128, 256, 0);
    // normalize + transpose + bf16 split
    k_norm<<<dim3(144, NB), 256, 0, stream>>>(feat, rf, hi, lo);
    // all-pairs sim + per-row off-diag argmax (8 column chunks)
    k_simtop<<<dim3(72, 8, NB), 256, 0, stream>>>(hi, lo, cval, cidx);
    // merge + exact distance + mask
    k_finish<<<1152, 256, 0, stream>>>(rf, cval, cidx, out);
}

// Round 3
// 289.153 us; speedup vs baseline: 1.1317x; 1.1317x over previous
//
#include <hip/hip_runtime.h>

#define NHW 9216   // 96*96
#define NB 2
#define NCHUNK 16  // col chunks for k_simtop

typedef short s8v __attribute__((ext_vector_type(8)));     // 8 bf16 in 4 VGPRs
typedef float f4v __attribute__((ext_vector_type(4)));

__device__ inline unsigned short f2bf(float x) {
    unsigned int u = __float_as_uint(x);
    u += 0x7fffu + ((u >> 16) & 1u);          // round-to-nearest-even
    return (unsigned short)(u >> 16);
}
__device__ inline float bf2f(unsigned short h) {
    return __uint_as_float(((unsigned int)h) << 16);
}

// ---------------------------------------------------------------------------
// K1/K2: fp32 SGEMM  C[b][m][n] = sum_k A[m][k] * B[b][k][n] + bias[m] (opt relu)
// tile 64(M) x 128(N), BK=16, block 256, micro 4x(4+4)
// ---------------------------------------------------------------------------
__global__ __launch_bounds__(256) void k_sgemm(const float* __restrict__ A,
                                               const float* __restrict__ Bm,
                                               const float* __restrict__ bias,
                                               float* __restrict__ C,
                                               int M, int K, int relu)
{
    __shared__ float As[16][68];    // As[k][m], padded
    __shared__ float Bs[16][132];   // Bs[k][n], padded
    const int tid = threadIdx.x;
    const int tm = tid >> 4, tn = tid & 15;
    const int b  = blockIdx.z;
    const int m0 = blockIdx.y * 64, n0 = blockIdx.x * 128;
    const float* Bb = Bm + (size_t)b * K * NHW;
    float*       Cb = C  + (size_t)b * M * NHW;

    float acc[4][8];
#pragma unroll
    for (int i = 0; i < 4; ++i)
#pragma unroll
        for (int j = 0; j < 8; ++j) acc[i][j] = 0.f;

    for (int kt = 0; kt < K; kt += 16) {
        __syncthreads();
#pragma unroll
        for (int r = 0; r < 4; ++r) {           // A tile 64x16 -> As[k][m]
            int e = r * 256 + tid;
            int m = e >> 4, kk = e & 15;
            As[kk][m] = A[(size_t)(m0 + m) * K + kt + kk];
        }
#pragma unroll
        for (int r = 0; r < 2; ++r) {           // B tile 16x128
            int e = r * 256 + tid;
            int kk = e >> 5, n4 = e & 31;
            *(f4v*)&Bs[kk][n4 * 4] = *(const f4v*)&Bb[(size_t)(kt + kk) * NHW + n0 + n4 * 4];
        }
        __syncthreads();
#pragma unroll
        for (int kk = 0; kk < 16; ++kk) {
            f4v a  = *(const f4v*)&As[kk][tm * 4];
            f4v b1 = *(const f4v*)&Bs[kk][tn * 4];
            f4v b2 = *(const f4v*)&Bs[kk][tn * 4 + 64];
#pragma unroll
            for (int i = 0; i < 4; ++i)
#pragma unroll
                for (int j = 0; j < 4; ++j) {
                    acc[i][j]     += a[i] * b1[j];
                    acc[i][j + 4] += a[i] * b2[j];
                }
        }
    }
#pragma unroll
    for (int i = 0; i < 4; ++i) {
        int m = m0 + tm * 4 + i;
        float bs = bias[m];
        f4v o1, o2;
#pragma unroll
        for (int j = 0; j < 4; ++j) {
            float v1 = acc[i][j] + bs, v2 = acc[i][j + 4] + bs;
            if (relu) { v1 = fmaxf(v1, 0.f); v2 = fmaxf(v2, 0.f); }
            o1[j] = v1; o2[j] = v2;
        }
        *(f4v*)&Cb[(size_t)m * NHW + n0 + tn * 4]      = o1;
        *(f4v*)&Cb[(size_t)m * NHW + n0 + tn * 4 + 64] = o2;
    }
}

// ---------------------------------------------------------------------------
// K2b: per-pixel L2 normalize + transpose (c-major -> pixel-major) + bf16 hi/lo split
// block 256 = 64 pixels x 4 channel-groups of 32
// ---------------------------------------------------------------------------
__global__ __launch_bounds__(256) void k_norm(const float* __restrict__ feat,
                                              float* __restrict__ rf,
                                              unsigned short* __restrict__ hi,
                                              unsigned short* __restrict__ lo)
{
    __shared__ float fs[128][66];
    const int tid = threadIdx.x;
    const int b = blockIdx.y;
    const int p0 = blockIdx.x * 64;
    const size_t fb = (size_t)b * 128 * NHW;
#pragma unroll
    for (int r = 0; r < 32; ++r) {
        int e = r * 256 + tid;
        int c = e >> 6, p = e & 63;
        fs[c][p] = feat[fb + (size_t)c * NHW + p0 + p];
    }
    __syncthreads();
    const int pix = tid >> 2, cg = tid & 3;
    const int c0 = cg * 32;
    float ss = 0.f;
#pragma unroll
    for (int i = 0; i < 32; ++i) { float v = fs[c0 + i][pix]; ss += v * v; }
    ss += __shfl_xor(ss, 1, 64);
    ss += __shfl_xor(ss, 2, 64);
    const float mx = fmaxf(sqrtf(ss), 1e-12f);
    const size_t ro = ((size_t)b * NHW + p0 + pix) * 128 + c0;
#pragma unroll
    for (int i = 0; i < 32; ++i) {
        float v = fs[c0 + i][pix] / mx;
        rf[ro + i] = v;
        unsigned short h = f2bf(v);
        hi[ro + i] = h;
        lo[ro + i] = f2bf(v - bf2f(h));
    }
}

// ---------------------------------------------------------------------------
// K3: sim = rf . rf^T via 3-term bf16-split MFMA, running off-diag argmax/row.
// block 256 (4 waves), 192 rows/block (48/wave, 3 subtiles), col chunk = 576
// (9 tiles of 64). Double-buffered LDS staged via global_load_lds width=16.
// ---------------------------------------------------------------------------
__global__ __launch_bounds__(256, 2) void k_simtop(const unsigned short* __restrict__ hi,
                                                   const unsigned short* __restrict__ lo,
                                                   float* __restrict__ cval,
                                                   int* __restrict__ cidx)
{
    // frag-contiguous staging: chunk id = split*16 + kf*4 + cs; each chunk 64 lanes x 16B
    __shared__ unsigned short Bs[2][32][512];   // 64 KB double buffer
    const int tid  = threadIdx.x;
    const int wave = tid >> 6, l = tid & 63, l15 = l & 15, q = l >> 4;
    const int b     = blockIdx.z;
    const int rbase = blockIdx.x * 192;
    const int chunk = blockIdx.y;
    const int cbase = chunk * 576;
    const size_t base = (size_t)b * NHW;
    const int wr0 = rbase + wave * 48;

    // A fragments in registers: 3 row-subtiles x 4 k-frags, hi+lo (96 VGPRs)
    s8v ah[3][4], al[3][4];
#pragma unroll
    for (int s = 0; s < 3; ++s) {
        int row = wr0 + s * 16 + l15;
#pragma unroll
        for (int kf = 0; kf < 4; ++kf) {
            int k = kf * 32 + q * 8;
            ah[s][kf] = *(const s8v*)&hi[(base + row) * 128 + k];
            al[s][kf] = *(const s8v*)&lo[(base + row) * 128 + k];
        }
    }

    // async stage of one 64-col tile (32 KB) into buffer `buf`
    auto stage = [&](int colt, int buf) {
#pragma unroll
        for (int r = 0; r < 8; ++r) {
            int cid = r * 4 + wave;
            int split = cid >> 4, kf = (cid >> 2) & 3, cs = cid & 3;
            int col = colt + cs * 16 + l15;
            const unsigned short* src =
                (split ? lo : hi) + (base + col) * 128 + kf * 32 + q * 8;
            __builtin_amdgcn_global_load_lds(
                (const __attribute__((address_space(1))) void*)src,
                (__attribute__((address_space(3))) void*)&Bs[buf][cid][0],
                16, 0, 0);
        }
    };

    float bv[3][4]; int bi[3][4];
#pragma unroll
    for (int s = 0; s < 3; ++s)
#pragma unroll
        for (int r = 0; r < 4; ++r) { bv[s][r] = -2.0f; bi[s][r] = 0; }

    stage(cbase, 0);
    __syncthreads();                             // drain initial stage

    for (int ct = 0; ct < 9; ++ct) {
        const int colt = cbase + ct * 64;
        const int buf  = ct & 1;
        if (ct < 8) stage(colt + 64, buf ^ 1);   // prefetch next tile (latency hidden by compute)

        f4v acc[3][4];
#pragma unroll
        for (int s = 0; s < 3; ++s)
#pragma unroll
            for (int c = 0; c < 4; ++c) acc[s][c] = (f4v){0.f, 0.f, 0.f, 0.f};

#pragma unroll
        for (int kf = 0; kf < 4; ++kf) {
            s8v bh[4], bl[4];
#pragma unroll
            for (int cs = 0; cs < 4; ++cs) {
                bh[cs] = *(const s8v*)&Bs[buf][kf * 4 + cs][l * 8];
                bl[cs] = *(const s8v*)&Bs[buf][16 + kf * 4 + cs][l * 8];
            }
#pragma unroll
            for (int cs = 0; cs < 4; ++cs)
#pragma unroll
                for (int s = 0; s < 3; ++s)
                    acc[s][cs] = __builtin_amdgcn_mfma_f32_16x16x32_bf16(ah[s][kf], bh[cs], acc[s][cs], 0, 0, 0);
#pragma unroll
            for (int cs = 0; cs < 4; ++cs)
#pragma unroll
                for (int s = 0; s < 3; ++s)
                    acc[s][cs] = __builtin_amdgcn_mfma_f32_16x16x32_bf16(ah[s][kf], bl[cs], acc[s][cs], 0, 0, 0);
#pragma unroll
            for (int cs = 0; cs < 4; ++cs)
#pragma unroll
                for (int s = 0; s < 3; ++s)
                    acc[s][cs] = __builtin_amdgcn_mfma_f32_16x16x32_bf16(al[s][kf], bh[cs], acc[s][cs], 0, 0, 0);
        }

        // running off-diagonal argmax (C layout: col = lane&15, row = q*4 + reg)
        const bool hasdiag = (colt < wr0 + 48) && (wr0 < colt + 64);
        if (hasdiag) {
#pragma unroll
            for (int s = 0; s < 3; ++s)
#pragma unroll
                for (int cs = 0; cs < 4; ++cs) {
                    int c = colt + cs * 16 + l15;
#pragma unroll
                    for (int r = 0; r < 4; ++r) {
                        float v = acc[s][cs][r];
                        int rr = wr0 + s * 16 + q * 4 + r;
                        bool p = (v > bv[s][r]) && (c != rr);
                        bv[s][r] = p ? v : bv[s][r];
                        bi[s][r] = p ? c : bi[s][r];
                    }
                }
        } else {
#pragma unroll
            for (int s = 0; s < 3; ++s)
#pragma unroll
                for (int cs = 0; cs < 4; ++cs) {
                    int c = colt + cs * 16 + l15;
#pragma unroll
                    for (int r = 0; r < 4; ++r) {
                        float v = acc[s][cs][r];
                        bool p = v > bv[s][r];
                        bv[s][r] = p ? v : bv[s][r];
                        bi[s][r] = p ? c : bi[s][r];
                    }
                }
        }
        __syncthreads();   // drains prefetch vmcnt + protects buffer reuse
    }

    // merge across the 16 lanes sharing each row (tie: lower index)
#pragma unroll
    for (int d = 1; d < 16; d <<= 1) {
#pragma unroll
        for (int s = 0; s < 3; ++s)
#pragma unroll
            for (int r = 0; r < 4; ++r) {
                float ov = __shfl_xor(bv[s][r], d, 64);
                int   oi = __shfl_xor(bi[s][r], d, 64);
                bool p = (ov > bv[s][r]) || (ov == bv[s][r] && oi < bi[s][r]);
                bv[s][r] = p ? ov : bv[s][r];
                bi[s][r] = p ? oi : bi[s][r];
            }
    }
    if (l15 == 0) {
#pragma unroll
        for (int s = 0; s < 3; ++s)
#pragma unroll
            for (int r = 0; r < 4; ++r) {
                int row = wr0 + s * 16 + q * 4 + r;
                cval[(base + row) * NCHUNK + chunk] = bv[s][r];
                cidx[(base + row) * NCHUNK + chunk] = bi[s][r];
            }
    }
}

// ---------------------------------------------------------------------------
// K4: merge chunk candidates per row, gather neighbor, exact fp32 distance + mask
// block 256 = 16 rows x 16 lanes
// ---------------------------------------------------------------------------
__global__ __launch_bounds__(256) void k_finish(const float* __restrict__ rf,
                                                const float* __restrict__ cval,
                                                const int* __restrict__ cidx,
                                                float* __restrict__ out)
{
    const int tid = threadIdx.x;
    const int g = blockIdx.x * 16 + (tid >> 4);   // global row in [0, 18432)
    const int l15 = tid & 15;
    const int b = g / NHW, r = g - b * NHW;

    float bvv = -2.f; int bii = 0;
#pragma unroll
    for (int ch = 0; ch < NCHUNK; ++ch) {
        float v = cval[(size_t)g * NCHUNK + ch];
        int   i = cidx[(size_t)g * NCHUNK + ch];
        bool p = (v > bvv) || (v == bvv && i < bii);
        bvv = p ? v : bvv;
        bii = p ? i : bii;
    }
    const float* x = rf + ((size_t)b * NHW + r)   * 128;
    const float* y = rf + ((size_t)b * NHW + bii) * 128;
    float ss = 0.f;
#pragma unroll
    for (int j = 0; j < 2; ++j) {
        f4v a = *(const f4v*)&x[l15 * 8 + j * 4];
        f4v c = *(const f4v*)&y[l15 * 8 + j * 4];
        float d0 = a[0] - c[0], d1 = a[1] - c[1], d2 = a[2] - c[2], d3 = a[3] - c[3];
        ss += d0 * d0 + d1 * d1 + d2 * d2 + d3 * d3;
    }
#pragma unroll
    for (int d = 1; d < 16; d <<= 1) ss += __shfl_xor(ss, d, 64);
    if (l15 == 0) {
        float dist = sqrtf(ss);
        out[NB * NHW + g] = dist;                 // distance (B, 9216)
        out[g] = dist > 0.2f ? 1.0f : 0.0f;       // mask (B,1,96,96)
    }
}

// ---------------------------------------------------------------------------
extern "C" void kernel_launch(void* const* d_in, const int* in_sizes, int n_in,
                              void* d_out, int out_size, void* d_ws, size_t ws_size,
                              hipStream_t stream) {
    const float* features = (const float*)d_in[0];
    const float* W1 = (const float*)d_in[1];
    const float* b1 = (const float*)d_in[2];
    const float* W2 = (const float*)d_in[3];
    const float* b2 = (const float*)d_in[4];
    float* out = (float*)d_out;
    float* ws  = (float*)d_ws;

    // ws layout (floats), peak usage 7,077,888 floats = 28.3 MB:
    //   [0,        2359296)  feat   (dead after k_norm -> reused by cval/cidx)
    //   [2359296,  7077888)  h      (dead after k_sgemm#2)
    //   [2359296,  4718592)  rf     (aliases h lower half)
    //   [4718592,  5898240)  hi     (2359296 shorts, aliases h upper half)
    //   [5898240,  7077888)  lo     (2359296 shorts)
    //   [0,        294912)   cval   (aliases feat — k_norm done before k_simtop)
    //   [294912,   589824)   cidx
    float*          feat = ws;
    float*          h    = ws + 2359296;
    float*          rf   = ws + 2359296;
    unsigned short* hi   = (unsigned short*)(ws + 4718592);
    unsigned short* lo   = hi + 2359296;
    float*          cval = ws;
    int*            cidx = (int*)(ws + 294912);

    // conv1: h = relu(W1 @ X + b1)    (M=256, K=384)
    k_sgemm<<<dim3(72, 4, NB), 256, 0, stream>>>(W1, features, b1, h, 256, 384, 1);
    // conv2: feat = W2 @ h + b2       (M=128, K=256)
    k_sgemm<<<dim3(72, 2, NB), 256, 0, stream>>>(W2, h, b2, feat, 128, 256, 0);
    // normalize + transpose + bf16 split
    k_norm<<<dim3(144, NB), 256, 0, stream>>>(feat, rf, hi, lo);
    // all-pairs sim + per-row off-diag argmax (16 column chunks of 576)
    k_simtop<<<dim3(48, NCHUNK, NB), 256, 0, stream>>>(hi, lo, cval, cidx);
    // merge + exact distance + mask
    k_finish<<<1152, 256, 0, stream>>>(rf, cval, cidx, out);
}

// Round 5
// 257.109 us; speedup vs baseline: 1.2727x; 1.1246x over previous
//
#include <hip/hip_runtime.h>

#define NHW 9216   // 96*96
#define NB 2
#define NCHUNK 16  // col chunks for k_simtop

typedef short s8v __attribute__((ext_vector_type(8)));       // 8x16-bit in 4 VGPRs
typedef _Float16 h8v __attribute__((ext_vector_type(8)));    // 8 f16
typedef float f4v __attribute__((ext_vector_type(4)));
typedef unsigned int u32;
typedef unsigned short u16;

__device__ inline u16 f2bf(float x) {
    u32 u = __float_as_uint(x);
    u += 0x7fffu + ((u >> 16) & 1u);          // round-to-nearest-even
    return (u16)(u >> 16);
}
__device__ inline float bf2f(u16 h) {
    return __uint_as_float(((u32)h) << 16);
}

// ---------------------------------------------------------------------------
// K1: conv1 h[g][256] = relu(X^T W1^T + b1) via f16 3-term-split MFMA.
// Fuses the transpose (features are c-major) and the f16 hi/lo split.
// block 256: 128 px x 64 couts; K-loop 6 tiles of 64, single-buffered LDS.
// All LDS access via direct indexing of one __shared__ union (no AS casts).
// ---------------------------------------------------------------------------
__global__ __launch_bounds__(256) void k_gemm1(const float* __restrict__ X,
                                               const float* __restrict__ W1,
                                               const float* __restrict__ b1,
                                               u16* __restrict__ oh, u16* __restrict__ ol)
{
    union SM {
        struct { float A[64 * 132]; u16 B[16 * 512]; } s;  // A: [c][px] pad132; B: frag chunks
        u32 bounce[128 * 65];                              // epilogue transpose buffer
    };
    __shared__ SM sm;
    const int tid = threadIdx.x;
    const int wave = tid >> 6, l = tid & 63, l15 = l & 15, q = l >> 4;
    const int g0 = blockIdx.x * 128;          // global pixel base (128 | 9216 -> no batch straddle)
    const int c0 = blockIdx.y * 64;           // cout base
    const int bb = g0 / NHW;
    const int hw0 = g0 - bb * NHW;
    const float* Xb = X + (size_t)bb * 384 * NHW;

    f4v acc[2][4];
#pragma unroll
    for (int s = 0; s < 2; ++s)
#pragma unroll
        for (int c = 0; c < 4; ++c) acc[s][c] = (f4v){0.f, 0.f, 0.f, 0.f};

    for (int t = 0; t < 6; ++t) {
        const int kt = t * 64;
        __syncthreads();
        // stage A: 64 c x 128 px fp32 (coalesced f4v over px; lane-consecutive 16B LDS writes)
#pragma unroll
        for (int r = 0; r < 8; ++r) {
            int idx = r * 256 + tid;
            int cc = idx >> 5, pp = idx & 31;
            *(f4v*)&sm.s.A[cc * 132 + pp * 4] =
                *(const f4v*)&Xb[(size_t)(kt + cc) * NHW + hw0 + pp * 4];
        }
        // stage W1: fp32 -> f16 hi/lo fragment chunks (chunk pc = kf*4+cs; lo at 8+pc)
#pragma unroll
        for (int r = 0; r < 2; ++r) {
            int pc = r * 4 + wave;
            int kf = pc >> 2, cs = pc & 3;
            const float* src = W1 + (size_t)(c0 + cs * 16 + l15) * 384 + kt + kf * 32 + q * 8;
            h8v hv, lv;
#pragma unroll
            for (int j = 0; j < 8; ++j) {
                float v = src[j];
                _Float16 h = (_Float16)v;
                hv[j] = h;
                lv[j] = (_Float16)(v - (float)h);
            }
            *(s8v*)&sm.s.B[pc * 512 + l * 8]       = *(s8v*)&hv;
            *(s8v*)&sm.s.B[(8 + pc) * 512 + l * 8] = *(s8v*)&lv;
        }
        __syncthreads();
        // compute: A read from LDS + register-convert, B fragments from LDS
#pragma unroll
        for (int kf = 0; kf < 2; ++kf) {
            h8v ah[2], al[2];
#pragma unroll
            for (int s = 0; s < 2; ++s) {
#pragma unroll
                for (int j = 0; j < 8; ++j) {
                    float v = sm.s.A[(kf * 32 + q * 8 + j) * 132 + wave * 32 + s * 16 + l15];
                    _Float16 h = (_Float16)v;
                    ah[s][j] = h;
                    al[s][j] = (_Float16)(v - (float)h);
                }
            }
            h8v bh[4], bl[4];
#pragma unroll
            for (int cs = 0; cs < 4; ++cs) {
                bh[cs] = *(const h8v*)&sm.s.B[(kf * 4 + cs) * 512 + l * 8];
                bl[cs] = *(const h8v*)&sm.s.B[(8 + kf * 4 + cs) * 512 + l * 8];
            }
#pragma unroll
            for (int cs = 0; cs < 4; ++cs)
#pragma unroll
                for (int s = 0; s < 2; ++s) {
                    acc[s][cs] = __builtin_amdgcn_mfma_f32_16x16x32_f16(ah[s], bh[cs], acc[s][cs], 0, 0, 0);
                    acc[s][cs] = __builtin_amdgcn_mfma_f32_16x16x32_f16(ah[s], bl[cs], acc[s][cs], 0, 0, 0);
                    acc[s][cs] = __builtin_amdgcn_mfma_f32_16x16x32_f16(al[s], bh[cs], acc[s][cs], 0, 0, 0);
                }
        }
    }
    __syncthreads();   // all waves done reading staging before bounce overwrite

    // epilogue: bias+relu, f16 hi/lo split, LDS bounce, coalesced [g][256] store
#pragma unroll
    for (int s = 0; s < 2; ++s)
#pragma unroll
        for (int cs = 0; cs < 4; ++cs) {
            int c = cs * 16 + l15;
            float bv = b1[c0 + c];
#pragma unroll
            for (int r = 0; r < 4; ++r) {
                float v = fmaxf(acc[s][cs][r] + bv, 0.f);
                _Float16 h = (_Float16)v;
                _Float16 lo = (_Float16)(v - (float)h);
                int px = wave * 32 + s * 16 + q * 4 + r;   // C-layout: row = q*4+reg, col = l15
                sm.bounce[px * 65 + c] = (u32)*(u16*)&h | ((u32)*(u16*)&lo << 16);
            }
        }
    __syncthreads();
    {
        int px = tid >> 1, half = tid & 1;
        u16 hb[32], lb[32];
#pragma unroll
        for (int i = 0; i < 32; ++i) {
            u32 p = sm.bounce[px * 65 + half * 32 + i];
            hb[i] = (u16)p; lb[i] = (u16)(p >> 16);
        }
        size_t o = (size_t)(g0 + px) * 256 + c0 + half * 32;
#pragma unroll
        for (int j = 0; j < 4; ++j) {
            *(s8v*)&oh[o + j * 8] = *(s8v*)&hb[j * 8];
            *(s8v*)&ol[o + j * 8] = *(s8v*)&lb[j * 8];
        }
    }
}

// ---------------------------------------------------------------------------
// K2: conv2 feat[g][128] = h W2^T + b2, f16 3-term MFMA, fp32 out.
// block 256: 64 px x 64 couts. Whole 64x256 W2 slice staged once (fp32->f16
// hi/lo, 64 KB LDS) -> barrier-free K-loop over 8 kf.
// ---------------------------------------------------------------------------
__global__ __launch_bounds__(256) void k_gemm2(const u16* __restrict__ hh, const u16* __restrict__ hl,
                                               const float* __restrict__ W2,
                                               const float* __restrict__ b2,
                                               float* __restrict__ feat)
{
    __shared__ u16 Bs[64 * 512];   // 64 chunks: hi at pc=kf*4+cs, lo at 32+pc
    const int tid = threadIdx.x;
    const int wave = tid >> 6, l = tid & 63, l15 = l & 15, q = l >> 4;
    const int g0 = blockIdx.x * 64;
    const int c0 = blockIdx.y * 64;

#pragma unroll
    for (int r = 0; r < 8; ++r) {
        int pc = r * 4 + wave;                 // [0,32): kf = pc>>2, cs = pc&3
        int kf = pc >> 2, cs = pc & 3;
        const float* src = W2 + (size_t)(c0 + cs * 16 + l15) * 256 + kf * 32 + q * 8;
        h8v hv, lv;
#pragma unroll
        for (int j = 0; j < 8; ++j) {
            float v = src[j];
            _Float16 h = (_Float16)v;
            hv[j] = h;
            lv[j] = (_Float16)(v - (float)h);
        }
        *(s8v*)&Bs[pc * 512 + l * 8]        = *(s8v*)&hv;
        *(s8v*)&Bs[(32 + pc) * 512 + l * 8] = *(s8v*)&lv;
    }
    __syncthreads();

    const int gw = g0 + wave * 16;
    f4v acc[4];
#pragma unroll
    for (int c = 0; c < 4; ++c) acc[c] = (f4v){0.f, 0.f, 0.f, 0.f};

#pragma unroll
    for (int kf = 0; kf < 8; ++kf) {
        size_t o = (size_t)(gw + l15) * 256 + kf * 32 + q * 8;
        h8v ah = *(const h8v*)&hh[o];
        h8v al = *(const h8v*)&hl[o];
        h8v bh[4], bl[4];
#pragma unroll
        for (int cs = 0; cs < 4; ++cs) {
            bh[cs] = *(const h8v*)&Bs[(kf * 4 + cs) * 512 + l * 8];
            bl[cs] = *(const h8v*)&Bs[(32 + kf * 4 + cs) * 512 + l * 8];
        }
#pragma unroll
        for (int cs = 0; cs < 4; ++cs) {
            acc[cs] = __builtin_amdgcn_mfma_f32_16x16x32_f16(ah, bh[cs], acc[cs], 0, 0, 0);
            acc[cs] = __builtin_amdgcn_mfma_f32_16x16x32_f16(ah, bl[cs], acc[cs], 0, 0, 0);
            acc[cs] = __builtin_amdgcn_mfma_f32_16x16x32_f16(al, bh[cs], acc[cs], 0, 0, 0);
        }
    }
#pragma unroll
    for (int cs = 0; cs < 4; ++cs) {
        float bv = b2[c0 + cs * 16 + l15];
#pragma unroll
        for (int r = 0; r < 4; ++r)
            feat[(size_t)(gw + q * 4 + r) * 128 + c0 + cs * 16 + l15] = acc[cs][r] + bv;
    }
}

// ---------------------------------------------------------------------------
// K3: normalize rows of feat [g][128] -> rf fp32 + bf16 hi/lo (for k_simtop)
// ---------------------------------------------------------------------------
__global__ __launch_bounds__(256) void k_norm2(const float* __restrict__ feat,
                                               float* __restrict__ rf,
                                               u16* __restrict__ hib, u16* __restrict__ lob)
{
    const int tid = threadIdx.x;
    const int px = blockIdx.x * 64 + (tid >> 2), part = tid & 3;
    const size_t o = (size_t)px * 128 + part * 32;
    f4v v[8];
    float ss = 0.f;
#pragma unroll
    for (int j = 0; j < 8; ++j) {
        v[j] = *(const f4v*)&feat[o + j * 4];
        ss += v[j][0]*v[j][0] + v[j][1]*v[j][1] + v[j][2]*v[j][2] + v[j][3]*v[j][3];
    }
    ss += __shfl_xor(ss, 1, 64);
    ss += __shfl_xor(ss, 2, 64);
    const float mx = fmaxf(sqrtf(ss), 1e-12f);
    u16 hb[32], lb[32];
#pragma unroll
    for (int j = 0; j < 8; ++j) {
        f4v w;
#pragma unroll
        for (int e = 0; e < 4; ++e) {
            float val = v[j][e] / mx;
            w[e] = val;
            u16 h = f2bf(val);
            hb[j * 4 + e] = h;
            lb[j * 4 + e] = f2bf(val - bf2f(h));
        }
        *(f4v*)&rf[o + j * 4] = w;
    }
#pragma unroll
    for (int j = 0; j < 4; ++j) {
        *(s8v*)&hib[o + j * 8] = *(s8v*)&hb[j * 8];
        *(s8v*)&lob[o + j * 8] = *(s8v*)&lb[j * 8];
    }
}

// ---------------------------------------------------------------------------
// K4: sim argmax via 3-term bf16-split MFMA (R3-proven, unchanged)
// ---------------------------------------------------------------------------
__global__ __launch_bounds__(256, 2) void k_simtop(const u16* __restrict__ hi,
                                                   const u16* __restrict__ lo,
                                                   float* __restrict__ cval,
                                                   int* __restrict__ cidx)
{
    __shared__ u16 Bs[2][32][512];
    const int tid  = threadIdx.x;
    const int wave = tid >> 6, l = tid & 63, l15 = l & 15, q = l >> 4;
    const int b     = blockIdx.z;
    const int rbase = blockIdx.x * 192;
    const int chunk = blockIdx.y;
    const int cbase = chunk * 576;
    const size_t base = (size_t)b * NHW;
    const int wr0 = rbase + wave * 48;

    s8v ah[3][4], al[3][4];
#pragma unroll
    for (int s = 0; s < 3; ++s) {
        int row = wr0 + s * 16 + l15;
#pragma unroll
        for (int kf = 0; kf < 4; ++kf) {
            int k = kf * 32 + q * 8;
            ah[s][kf] = *(const s8v*)&hi[(base + row) * 128 + k];
            al[s][kf] = *(const s8v*)&lo[(base + row) * 128 + k];
        }
    }

    auto stage = [&](int colt, int buf) {
#pragma unroll
        for (int r = 0; r < 8; ++r) {
            int cid = r * 4 + wave;
            int split = cid >> 4, kf = (cid >> 2) & 3, cs = cid & 3;
            int col = colt + cs * 16 + l15;
            const u16* src = (split ? lo : hi) + (base + col) * 128 + kf * 32 + q * 8;
            __builtin_amdgcn_global_load_lds(
                (const __attribute__((address_space(1))) void*)src,
                (__attribute__((address_space(3))) void*)&Bs[buf][cid][0],
                16, 0, 0);
        }
    };

    float bv[3][4]; int bi[3][4];
#pragma unroll
    for (int s = 0; s < 3; ++s)
#pragma unroll
        for (int r = 0; r < 4; ++r) { bv[s][r] = -2.0f; bi[s][r] = 0; }

    stage(cbase, 0);
    __syncthreads();

    for (int ct = 0; ct < 9; ++ct) {
        const int colt = cbase + ct * 64;
        const int buf  = ct & 1;
        if (ct < 8) stage(colt + 64, buf ^ 1);

        f4v acc[3][4];
#pragma unroll
        for (int s = 0; s < 3; ++s)
#pragma unroll
            for (int c = 0; c < 4; ++c) acc[s][c] = (f4v){0.f, 0.f, 0.f, 0.f};

#pragma unroll
        for (int kf = 0; kf < 4; ++kf) {
            s8v bh[4], bl[4];
#pragma unroll
            for (int cs = 0; cs < 4; ++cs) {
                bh[cs] = *(const s8v*)&Bs[buf][kf * 4 + cs][l * 8];
                bl[cs] = *(const s8v*)&Bs[buf][16 + kf * 4 + cs][l * 8];
            }
#pragma unroll
            for (int cs = 0; cs < 4; ++cs)
#pragma unroll
                for (int s = 0; s < 3; ++s)
                    acc[s][cs] = __builtin_amdgcn_mfma_f32_16x16x32_bf16(ah[s][kf], bh[cs], acc[s][cs], 0, 0, 0);
#pragma unroll
            for (int cs = 0; cs < 4; ++cs)
#pragma unroll
                for (int s = 0; s < 3; ++s)
                    acc[s][cs] = __builtin_amdgcn_mfma_f32_16x16x32_bf16(ah[s][kf], bl[cs], acc[s][cs], 0, 0, 0);
#pragma unroll
            for (int cs = 0; cs < 4; ++cs)
#pragma unroll
                for (int s = 0; s < 3; ++s)
                    acc[s][cs] = __builtin_amdgcn_mfma_f32_16x16x32_bf16(al[s][kf], bh[cs], acc[s][cs], 0, 0, 0);
        }

        const bool hasdiag = (colt < wr0 + 48) && (wr0 < colt + 64);
        if (hasdiag) {
#pragma unroll
            for (int s = 0; s < 3; ++s)
#pragma unroll
                for (int cs = 0; cs < 4; ++cs) {
                    int c = colt + cs * 16 + l15;
#pragma unroll
                    for (int r = 0; r < 4; ++r) {
                        float v = acc[s][cs][r];
                        int rr = wr0 + s * 16 + q * 4 + r;
                        bool p = (v > bv[s][r]) && (c != rr);
                        bv[s][r] = p ? v : bv[s][r];
                        bi[s][r] = p ? c : bi[s][r];
                    }
                }
        } else {
#pragma unroll
            for (int s = 0; s < 3; ++s)
#pragma unroll
                for (int cs = 0; cs < 4; ++cs) {
                    int c = colt + cs * 16 + l15;
#pragma unroll
                    for (int r = 0; r < 4; ++r) {
                        float v = acc[s][cs][r];
                        bool p = v > bv[s][r];
                        bv[s][r] = p ? v : bv[s][r];
                        bi[s][r] = p ? c : bi[s][r];
                    }
                }
        }
        __syncthreads();
    }

#pragma unroll
    for (int d = 1; d < 16; d <<= 1) {
#pragma unroll
        for (int s = 0; s < 3; ++s)
#pragma unroll
            for (int r = 0; r < 4; ++r) {
                float ov = __shfl_xor(bv[s][r], d, 64);
                int   oi = __shfl_xor(bi[s][r], d, 64);
                bool p = (ov > bv[s][r]) || (ov == bv[s][r] && oi < bi[s][r]);
                bv[s][r] = p ? ov : bv[s][r];
                bi[s][r] = p ? oi : bi[s][r];
            }
    }
    if (l15 == 0) {
#pragma unroll
        for (int s = 0; s < 3; ++s)
#pragma unroll
            for (int r = 0; r < 4; ++r) {
                int row = wr0 + s * 16 + q * 4 + r;
                cval[(base + row) * NCHUNK + chunk] = bv[s][r];
                cidx[(base + row) * NCHUNK + chunk] = bi[s][r];
            }
    }
}

// ---------------------------------------------------------------------------
// K5: merge candidates, exact fp32 distance + mask (R3-proven, unchanged)
// ---------------------------------------------------------------------------
__global__ __launch_bounds__(256) void k_finish(const float* __restrict__ rf,
                                                const float* __restrict__ cval,
                                                const int* __restrict__ cidx,
                                                float* __restrict__ out)
{
    const int tid = threadIdx.x;
    const int g = blockIdx.x * 16 + (tid >> 4);
    const int l15 = tid & 15;
    const int b = g / NHW, r = g - b * NHW;

    float bvv = -2.f; int bii = 0;
#pragma unroll
    for (int ch = 0; ch < NCHUNK; ++ch) {
        float v = cval[(size_t)g * NCHUNK + ch];
        int   i = cidx[(size_t)g * NCHUNK + ch];
        bool p = (v > bvv) || (v == bvv && i < bii);
        bvv = p ? v : bvv;
        bii = p ? i : bii;
    }
    const float* x = rf + ((size_t)b * NHW + r)   * 128;
    const float* y = rf + ((size_t)b * NHW + bii) * 128;
    float ss = 0.f;
#pragma unroll
    for (int j = 0; j < 2; ++j) {
        f4v a = *(const f4v*)&x[l15 * 8 + j * 4];
        f4v c = *(const f4v*)&y[l15 * 8 + j * 4];
        float d0 = a[0] - c[0], d1 = a[1] - c[1], d2 = a[2] - c[2], d3 = a[3] - c[3];
        ss += d0 * d0 + d1 * d1 + d2 * d2 + d3 * d3;
    }
#pragma unroll
    for (int d = 1; d < 16; d <<= 1) ss += __shfl_xor(ss, d, 64);
    if (l15 == 0) {
        float dist = sqrtf(ss);
        out[NB * NHW + g] = dist;
        out[g] = dist > 0.2f ? 1.0f : 0.0f;
    }
}

// ===========================================================================
extern "C" void kernel_launch(void* const* d_in, const int* in_sizes, int n_in,
                              void* d_out, int out_size, void* d_ws, size_t ws_size,
                              hipStream_t stream) {
    const float* features = (const float*)d_in[0];
    const float* W1 = (const float*)d_in[1];
    const float* b1 = (const float*)d_in[2];
    const float* W2 = (const float*)d_in[3];
    const float* b2 = (const float*)d_in[4];
    float* out = (float*)d_out;
    float* ws  = (float*)d_ws;

    // ws layout (float offsets), peak 7,077,888 floats = 28,311,552 B (R3-proven):
    //   [0,       2359296)  hh (f16 bits)   -> after gemm2: rf
    //   [2359296, 4718592)  hl (f16 bits)   -> after gemm2: hib/lob (bf16)
    //   [4718592, 7077888)  feat (fp32)     -> after norm2: cval/cidx
    u16*   hh   = (u16*)ws;
    u16*   hl   = (u16*)(ws + 2359296);
    float* feat = ws + 4718592;
    float* rf   = ws;
    u16*   hib  = (u16*)(ws + 2359296);
    u16*   lob  = (u16*)(ws + 3538944);
    float* cval = ws + 4718592;
    int*   cidx = (int*)(ws + 5013504);

    // conv1 (fused transpose + f16 split), M=256 couts
    k_gemm1<<<dim3(144, 4), 256, 0, stream>>>(features, W1, b1, hh, hl);
    // conv2, M=128 couts, fp32 out pixel-major
    k_gemm2<<<dim3(288, 2), 256, 0, stream>>>(hh, hl, W2, b2, feat);
    // L2 normalize + bf16 hi/lo split
    k_norm2<<<288, 256, 0, stream>>>(feat, rf, hib, lob);
    // all-pairs sim + per-row off-diag argmax (16 column chunks of 576)
    k_simtop<<<dim3(48, NCHUNK, NB), 256, 0, stream>>>(hib, lob, cval, cidx);
    // merge + exact distance + mask
    k_finish<<<1152, 256, 0, stream>>>(rf, cval, cidx, out);
}